// Round 1
// baseline (570.797 us; speedup 1.0000x reference)
//
#include <hip/hip_runtime.h>
#include <math.h>

#define NT 768
#define CD 384
#define CZD 128
#define NH 16
#define CHD 24
#define HCD 384

// ---- K0: LayerNorm(a) rows + fold LN(z) constants: Wp = w*Wz, P = sum w*Wz, Q = sum b*Wz
__global__ __launch_bounds__(64) void k_prep(
    const float* __restrict__ a, const float* __restrict__ law, const float* __restrict__ lab,
    const float* __restrict__ lzw, const float* __restrict__ lzb, const float* __restrict__ Wz,
    float* __restrict__ an, float* __restrict__ Wp, float* __restrict__ PQ)
{
    const int b = blockIdx.x;
    const int lane = threadIdx.x;
    if (b < NT) {
        const float* row = a + b * CD;
        float v[6]; float s = 0.f, sq = 0.f;
        #pragma unroll
        for (int k = 0; k < 6; ++k) { float x = row[lane + 64*k]; v[k] = x; s += x; sq += x*x; }
        #pragma unroll
        for (int off = 32; off >= 1; off >>= 1) { s += __shfl_xor(s, off); sq += __shfl_xor(sq, off); }
        const float mu = s * (1.f/CD);
        const float rs = rsqrtf(sq * (1.f/CD) - mu*mu + 1e-5f);
        #pragma unroll
        for (int k = 0; k < 6; ++k) {
            int c = lane + 64*k;
            an[b*CD + c] = (v[k] - mu) * rs * law[c] + lab[c];
        }
    } else {
        for (int idx = lane; idx < CZD*NH; idx += 64)
            Wp[idx] = lzw[idx >> 4] * Wz[idx];
        if (lane < NH) {
            float P = 0.f, Q = 0.f;
            for (int c = 0; c < CZD; ++c) {
                P += lzw[c] * Wz[c*NH + lane];
                Q += lzb[c] * Wz[c*NH + lane];
            }
            PQ[lane] = P; PQ[NH + lane] = Q;
        }
    }
}

// ---- K1: projections q,k,v,g = an @ {Wq,Wk,Wv,Wg} (f32 tiled GEMM, 64x64 tile, 4x4/thread)
__global__ __launch_bounds__(256) void k_proj(
    const float* __restrict__ an, const float* __restrict__ Wq, const float* __restrict__ Wk,
    const float* __restrict__ Wv, const float* __restrict__ Wg, const float* __restrict__ bg,
    float* __restrict__ qm, float* __restrict__ kT, float* __restrict__ vT, float* __restrict__ gm)
{
    __shared__ float4 At[16][17];   // A^T tile: [kk][i/4]
    __shared__ float4 Bt[16][17];   // B tile:   [kk][n/4]
    const int ct = blockIdx.x;              // 24 = 4 matrices x 6 col-tiles
    const int mat = ct / 6;
    const int n0 = (ct % 6) * 64;
    const int i0 = blockIdx.y * 64;
    const float* __restrict__ W = (mat == 0) ? Wq : (mat == 1) ? Wk : (mat == 2) ? Wv : Wg;
    const int t = threadIdx.x;
    const int tr = t >> 4, tc = t & 15;
    float acc[4][4] = {};
    float* Atf = (float*)At;
    float* Btf = (float*)Bt;
    const int kkA = t & 15, iA = t >> 4;
    const int kkB = t >> 6, nB = t & 63;
    for (int k0 = 0; k0 < CD; k0 += 16) {
        __syncthreads();
        #pragma unroll
        for (int s = 0; s < 4; ++s)
            Atf[kkA*68 + iA + 16*s] = an[(i0 + iA + 16*s)*CD + k0 + kkA];
        #pragma unroll
        for (int s = 0; s < 4; ++s)
            Btf[(kkB + 4*s)*68 + nB] = W[(k0 + kkB + 4*s)*HCD + n0 + nB];
        __syncthreads();
        #pragma unroll
        for (int kk = 0; kk < 16; ++kk) {
            const float4 a4 = At[kk][tr];
            const float4 b4 = Bt[kk][tc];
            acc[0][0] += a4.x*b4.x; acc[0][1] += a4.x*b4.y; acc[0][2] += a4.x*b4.z; acc[0][3] += a4.x*b4.w;
            acc[1][0] += a4.y*b4.x; acc[1][1] += a4.y*b4.y; acc[1][2] += a4.y*b4.z; acc[1][3] += a4.y*b4.w;
            acc[2][0] += a4.z*b4.x; acc[2][1] += a4.z*b4.y; acc[2][2] += a4.z*b4.z; acc[2][3] += a4.z*b4.w;
            acc[3][0] += a4.w*b4.x; acc[3][1] += a4.w*b4.y; acc[3][2] += a4.w*b4.z; acc[3][3] += a4.w*b4.w;
        }
    }
    #pragma unroll
    for (int r = 0; r < 4; ++r) {
        const int i = i0 + tr*4 + r;
        #pragma unroll
        for (int c = 0; c < 4; ++c) {
            const int n = n0 + tc*4 + c;
            const float v = acc[r][c];
            if (mat == 0)      qm[i*HCD + n] = v * 0.20412414523193154f;           // * CH^-0.5
            else if (mat == 1) kT[n*NT + i] = v;                                   // k transposed
            else if (mat == 2) vT[n*NT + i] = v;                                   // v transposed
            else               gm[i*HCD + n] = 1.f / (1.f + __expf(-(v + bg[n]))); // sigmoid gate
        }
    }
}

// ---- K2: pair bias. bias[h][i][j] = rs*(S_h - mu*P_h) + Q_h, S_h = z[i,j,:].(w*Wz[:,h])
// 1 wave per block, 128 (i,j) rows per block, 2 rows per lane, c staged in quarters.
__global__ __launch_bounds__(64) void k_bias(
    const float* __restrict__ z, const float* __restrict__ Wp, const float* __restrict__ PQ,
    float* __restrict__ bias)
{
    __shared__ float zt[128*35];   // [row][cc], stride 35 -> bank (3*row+cc)%32, conflict-light
    const int lane = threadIdx.x;
    const size_t r0 = (size_t)blockIdx.x * 128;
    const int i  = (int)(r0 / NT);
    const int j0 = (int)(r0 % NT);
    float s1 = 0.f, q1 = 0.f, s2 = 0.f, q2 = 0.f;
    float acc1[16] = {}, acc2[16] = {};
    const float4* __restrict__ Wp4 = (const float4*)Wp;
    for (int cq = 0; cq < 4; ++cq) {
        __syncthreads();
        const float* src = z + r0*CZD + cq*32;
        #pragma unroll
        for (int s = 0; s < 16; ++s) {
            const int g = lane + 64*s;
            const int row = g >> 3, c4 = g & 7;
            const float4 v = *(const float4*)(src + (size_t)row*CZD + c4*4);
            const int base = row*35 + c4*4;
            zt[base+0] = v.x; zt[base+1] = v.y; zt[base+2] = v.z; zt[base+3] = v.w;
        }
        __syncthreads();
        #pragma unroll 2
        for (int cc = 0; cc < 32; ++cc) {
            const int c = cq*32 + cc;
            const float z1 = zt[lane*35 + cc];
            const float z2 = zt[(lane+64)*35 + cc];
            s1 += z1; q1 += z1*z1; s2 += z2; q2 += z2*z2;
            // wave-uniform weight loads (scalar-load candidates; 8 KB, cache-hot)
            const float4 w0 = Wp4[c*4+0], w1 = Wp4[c*4+1], w2 = Wp4[c*4+2], w3 = Wp4[c*4+3];
            acc1[0]+=z1*w0.x;  acc1[1]+=z1*w0.y;  acc1[2]+=z1*w0.z;  acc1[3]+=z1*w0.w;
            acc1[4]+=z1*w1.x;  acc1[5]+=z1*w1.y;  acc1[6]+=z1*w1.z;  acc1[7]+=z1*w1.w;
            acc1[8]+=z1*w2.x;  acc1[9]+=z1*w2.y;  acc1[10]+=z1*w2.z; acc1[11]+=z1*w2.w;
            acc1[12]+=z1*w3.x; acc1[13]+=z1*w3.y; acc1[14]+=z1*w3.z; acc1[15]+=z1*w3.w;
            acc2[0]+=z2*w0.x;  acc2[1]+=z2*w0.y;  acc2[2]+=z2*w0.z;  acc2[3]+=z2*w0.w;
            acc2[4]+=z2*w1.x;  acc2[5]+=z2*w1.y;  acc2[6]+=z2*w1.z;  acc2[7]+=z2*w1.w;
            acc2[8]+=z2*w2.x;  acc2[9]+=z2*w2.y;  acc2[10]+=z2*w2.z; acc2[11]+=z2*w2.w;
            acc2[12]+=z2*w3.x; acc2[13]+=z2*w3.y; acc2[14]+=z2*w3.z; acc2[15]+=z2*w3.w;
        }
    }
    float Pr[16], Qr[16];
    #pragma unroll
    for (int h = 0; h < 16; ++h) { Pr[h] = PQ[h]; Qr[h] = PQ[16+h]; }
    float mu = s1 * 0.0078125f;
    float rs = rsqrtf(q1 * 0.0078125f - mu*mu + 1e-5f);
    #pragma unroll
    for (int h = 0; h < 16; ++h)
        bias[(size_t)h*NT*NT + (size_t)i*NT + j0 + lane] = rs*(acc1[h] - mu*Pr[h]) + Qr[h];
    mu = s2 * 0.0078125f;
    rs = rsqrtf(q2 * 0.0078125f - mu*mu + 1e-5f);
    #pragma unroll
    for (int h = 0; h < 16; ++h)
        bias[(size_t)h*NT*NT + (size_t)i*NT + j0 + 64 + lane] = rs*(acc2[h] - mu*Pr[h]) + Qr[h];
}

// ---- K3: flash attention with pair bias. Block = (head, 64-row q-tile), 512 threads.
// Thread owns rows {i2, i2+32} and 4 key columns per 64-wide k-tile; fully per-thread
// online softmax, merged at the end (shfl pair-merge, then LDS merge of 8 partials).
__global__ __launch_bounds__(512) void k_attn(
    const float* __restrict__ qm, const float* __restrict__ kT, const float* __restrict__ vT,
    const float* __restrict__ bias, const float* __restrict__ mask, float* __restrict__ om)
{
    __shared__ __align__(16) char smem[55296];
    float (*ks)[68] = (float(*)[68])smem;                 // 24*68*4  = 6528
    float (*vs)[28] = (float(*)[28])(smem + 6528);        // 64*28*4  = 7168
    float (*qs)[25] = (float(*)[25])(smem + 13696);       // 64*25*4  = 6400
    float* mb       = (float*)(smem + 20096);             // 64*4     = 256
    // reused after the tile loop (guarded by a barrier):
    float (*po)[64][25] = (float(*)[64][25])smem;         // 8*64*25*4 = 51200
    float* pmf      = (float*)(smem + 51200);             // 8*64*4    = 2048
    float* plf      = (float*)(smem + 53248);             // 8*64*4    = 2048

    const int h  = blockIdx.x;
    const int i0 = blockIdx.y * 64;
    const int t = threadIdx.x;
    const int lane = t & 63, wave = t >> 6;
    const int i2 = lane & 31;
    const int jg4 = ((wave << 1) + (lane >> 5)) * 4;   // this thread's 4 key cols in tile

    for (int idx = t; idx < 64*CHD; idx += 512) {
        const int ii = idx / CHD, c = idx % CHD;
        qs[ii][c] = qm[(i0+ii)*HCD + h*CHD + c];
    }
    __syncthreads();
    float qr[2][24];
    #pragma unroll
    for (int c = 0; c < 24; ++c) { qr[0][c] = qs[i2][c]; qr[1][c] = qs[i2+32][c]; }
    float m_[2] = {-1e30f, -1e30f}, l_[2] = {0.f, 0.f};
    float ov[2][24] = {};

    for (int jt = 0; jt < NT; jt += 64) {
        __syncthreads();
        for (int idx = t; idx < 24*64; idx += 512) {
            const int c = idx >> 6, j = idx & 63;
            ks[c][j] = kT[(h*CHD + c)*NT + jt + j];
            vs[j][c] = vT[(h*CHD + c)*NT + jt + j];
        }
        if (t < 64) mb[t] = 1e9f * (mask[jt + t] - 1.f);
        __syncthreads();

        const float* bp = bias + ((size_t)h*NT + (size_t)(i0 + i2))*NT + jt + jg4;
        const float4 b0 = *(const float4*)bp;
        const float4 b1 = *(const float4*)(bp + 32*NT);
        float sc0[4] = {b0.x, b0.y, b0.z, b0.w};
        float sc1[4] = {b1.x, b1.y, b1.z, b1.w};
        #pragma unroll
        for (int jj = 0; jj < 4; ++jj) { const float m0 = mb[jg4+jj]; sc0[jj] += m0; sc1[jj] += m0; }
        #pragma unroll
        for (int c = 0; c < 24; ++c) {
            const float4 k4 = *(const float4*)&ks[c][jg4];
            const float q0 = qr[0][c], q1v = qr[1][c];
            sc0[0] += q0*k4.x;  sc0[1] += q0*k4.y;  sc0[2] += q0*k4.z;  sc0[3] += q0*k4.w;
            sc1[0] += q1v*k4.x; sc1[1] += q1v*k4.y; sc1[2] += q1v*k4.z; sc1[3] += q1v*k4.w;
        }
        const float mt0 = fmaxf(fmaxf(sc0[0], sc0[1]), fmaxf(sc0[2], sc0[3]));
        const float mt1 = fmaxf(fmaxf(sc1[0], sc1[1]), fmaxf(sc1[2], sc1[3]));
        const float mn0 = fmaxf(m_[0], mt0), mn1 = fmaxf(m_[1], mt1);
        const float al0 = __expf(m_[0] - mn0), al1 = __expf(m_[1] - mn1);
        m_[0] = mn0; m_[1] = mn1;
        float p0[4], p1[4];
        #pragma unroll
        for (int jj = 0; jj < 4; ++jj) { p0[jj] = __expf(sc0[jj] - mn0); p1[jj] = __expf(sc1[jj] - mn1); }
        l_[0] = l_[0]*al0 + (p0[0]+p0[1]+p0[2]+p0[3]);
        l_[1] = l_[1]*al1 + (p1[0]+p1[1]+p1[2]+p1[3]);
        #pragma unroll
        for (int c = 0; c < 24; ++c) { ov[0][c] *= al0; ov[1][c] *= al1; }
        #pragma unroll
        for (int jj = 0; jj < 4; ++jj) {
            #pragma unroll
            for (int c4 = 0; c4 < 6; ++c4) {
                const float4 v4 = *(const float4*)&vs[jg4+jj][c4*4];
                ov[0][c4*4+0] += p0[jj]*v4.x; ov[0][c4*4+1] += p0[jj]*v4.y;
                ov[0][c4*4+2] += p0[jj]*v4.z; ov[0][c4*4+3] += p0[jj]*v4.w;
                ov[1][c4*4+0] += p1[jj]*v4.x; ov[1][c4*4+1] += p1[jj]*v4.y;
                ov[1][c4*4+2] += p1[jj]*v4.z; ov[1][c4*4+3] += p1[jj]*v4.w;
            }
        }
    }
    // pair-merge the two half-wave partials (same rows, neighboring j-groups)
    #pragma unroll
    for (int r = 0; r < 2; ++r) {
        const float mo = __shfl_xor(m_[r], 32);
        const float lo = __shfl_xor(l_[r], 32);
        const float mn = fmaxf(m_[r], mo);
        const float wa = __expf(m_[r] - mn), wb = __expf(mo - mn);
        l_[r] = l_[r]*wa + lo*wb;
        m_[r] = mn;
        #pragma unroll
        for (int c = 0; c < 24; ++c)
            ov[r][c] = ov[r][c]*wa + __shfl_xor(ov[r][c], 32)*wb;
    }
    __syncthreads();   // tile-loop LDS reads done; smem reused for partials
    if (lane < 32) {
        #pragma unroll
        for (int r = 0; r < 2; ++r) {
            const int i = i2 + 32*r;
            pmf[wave*64 + i] = m_[r]; plf[wave*64 + i] = l_[r];
            #pragma unroll
            for (int c = 0; c < 24; ++c) po[wave][i][c] = ov[r][c];
        }
    }
    __syncthreads();
    {
        const int i = t & 63, cq = t >> 6;   // cq 0..7 -> 3 channels each
        float ms = -1e30f;
        #pragma unroll
        for (int g = 0; g < 8; ++g) ms = fmaxf(ms, pmf[g*64 + i]);
        float ls = 0.f, o0 = 0.f, o1 = 0.f, o2 = 0.f;
        #pragma unroll
        for (int g = 0; g < 8; ++g) {
            const float w = __expf(pmf[g*64 + i] - ms);
            ls += w * plf[g*64 + i];
            o0 += w * po[g][i][cq*3+0];
            o1 += w * po[g][i][cq*3+1];
            o2 += w * po[g][i][cq*3+2];
        }
        const float inv = 1.f / ls;
        float* dst = om + (size_t)(i0 + i)*HCD + h*CHD + cq*3;
        dst[0] = o0*inv; dst[1] = o1*inv; dst[2] = o2*inv;
    }
}

// ---- K4: out = (g*o) @ Wo + bo (f32 tiled GEMM with fused gating)
__global__ __launch_bounds__(256) void k_epi(
    const float* __restrict__ gm, const float* __restrict__ om, const float* __restrict__ Wo,
    const float* __restrict__ bo, float* __restrict__ out)
{
    __shared__ float4 At[16][17];
    __shared__ float4 Bt[16][17];
    const int n0 = blockIdx.x * 64;
    const int i0 = blockIdx.y * 64;
    const int t = threadIdx.x;
    const int tr = t >> 4, tc = t & 15;
    float acc[4][4] = {};
    float* Atf = (float*)At;
    float* Btf = (float*)Bt;
    const int kkA = t & 15, iA = t >> 4;
    const int kkB = t >> 6, nB = t & 63;
    for (int k0 = 0; k0 < HCD; k0 += 16) {
        __syncthreads();
        #pragma unroll
        for (int s = 0; s < 4; ++s) {
            const int row = i0 + iA + 16*s;
            Atf[kkA*68 + iA + 16*s] = gm[row*HCD + k0 + kkA] * om[row*HCD + k0 + kkA];
        }
        #pragma unroll
        for (int s = 0; s < 4; ++s)
            Btf[(kkB + 4*s)*68 + nB] = Wo[(k0 + kkB + 4*s)*CD + n0 + nB];
        __syncthreads();
        #pragma unroll
        for (int kk = 0; kk < 16; ++kk) {
            const float4 a4 = At[kk][tr];
            const float4 b4 = Bt[kk][tc];
            acc[0][0] += a4.x*b4.x; acc[0][1] += a4.x*b4.y; acc[0][2] += a4.x*b4.z; acc[0][3] += a4.x*b4.w;
            acc[1][0] += a4.y*b4.x; acc[1][1] += a4.y*b4.y; acc[1][2] += a4.y*b4.z; acc[1][3] += a4.y*b4.w;
            acc[2][0] += a4.z*b4.x; acc[2][1] += a4.z*b4.y; acc[2][2] += a4.z*b4.z; acc[2][3] += a4.z*b4.w;
            acc[3][0] += a4.w*b4.x; acc[3][1] += a4.w*b4.y; acc[3][2] += a4.w*b4.z; acc[3][3] += a4.w*b4.w;
        }
    }
    #pragma unroll
    for (int r = 0; r < 4; ++r) {
        const int i = i0 + tr*4 + r;
        #pragma unroll
        for (int c = 0; c < 4; ++c) {
            const int n = n0 + tc*4 + c;
            out[i*CD + n] = acc[r][c] + bo[n];
        }
    }
}

extern "C" void kernel_launch(void* const* d_in, const int* in_sizes, int n_in,
                              void* d_out, int out_size, void* d_ws, size_t ws_size,
                              hipStream_t stream) {
    const float* a    = (const float*)d_in[0];
    const float* z    = (const float*)d_in[1];
    const float* mask = (const float*)d_in[2];
    const float* law  = (const float*)d_in[3];
    const float* lab  = (const float*)d_in[4];
    const float* lzw  = (const float*)d_in[5];
    const float* lzb  = (const float*)d_in[6];
    const float* Wz   = (const float*)d_in[7];
    const float* Wq   = (const float*)d_in[8];
    const float* Wk   = (const float*)d_in[9];
    const float* Wv   = (const float*)d_in[10];
    const float* Wg   = (const float*)d_in[11];
    const float* bg   = (const float*)d_in[12];
    const float* Wo   = (const float*)d_in[13];
    const float* bo   = (const float*)d_in[14];
    float* out = (float*)d_out;

    float* ws = (float*)d_ws;
    float* an   = ws;                  // 768*384
    float* qm   = an + 294912;
    float* kT   = qm + 294912;
    float* vT   = kT + 294912;
    float* gm   = vT + 294912;
    float* om   = gm + 294912;
    float* Wp   = om + 294912;         // 128*16
    float* PQ   = Wp + 2048;           // 32
    float* bias = PQ + 32;             // 16*768*768

    k_prep<<<769, 64, 0, stream>>>(a, law, lab, lzw, lzb, Wz, an, Wp, PQ);
    k_proj<<<dim3(24, 12), 256, 0, stream>>>(an, Wq, Wk, Wv, Wg, bg, qm, kT, vT, gm);
    k_bias<<<4608, 64, 0, stream>>>(z, Wp, PQ, bias);
    k_attn<<<dim3(16, 12), 512, 0, stream>>>(qm, kT, vT, bias, mask, om);
    k_epi<<<dim3(6, 12), 256, 0, stream>>>(gm, om, Wo, bo, out);
}

// Round 2
// 567.515 us; speedup vs baseline: 1.0058x; 1.0058x over previous
//
#include <hip/hip_runtime.h>
#include <math.h>

#define NT 768
#define CD 384
#define CZD 128
#define NH 16
#define CHD 24
#define HCD 384

// ---- K0: LayerNorm(a) rows + fold LN(z) constants: Wp = w*Wz, P = sum w*Wz, Q = sum b*Wz
__global__ __launch_bounds__(64) void k_prep(
    const float* __restrict__ a, const float* __restrict__ law, const float* __restrict__ lab,
    const float* __restrict__ lzw, const float* __restrict__ lzb, const float* __restrict__ Wz,
    float* __restrict__ an, float* __restrict__ Wp, float* __restrict__ PQ)
{
    const int b = blockIdx.x;
    const int lane = threadIdx.x;
    if (b < NT) {
        const float* row = a + b * CD;
        float v[6]; float s = 0.f, sq = 0.f;
        #pragma unroll
        for (int k = 0; k < 6; ++k) { float x = row[lane + 64*k]; v[k] = x; s += x; sq += x*x; }
        #pragma unroll
        for (int off = 32; off >= 1; off >>= 1) { s += __shfl_xor(s, off); sq += __shfl_xor(sq, off); }
        const float mu = s * (1.f/CD);
        const float rs = rsqrtf(sq * (1.f/CD) - mu*mu + 1e-5f);
        #pragma unroll
        for (int k = 0; k < 6; ++k) {
            int c = lane + 64*k;
            an[b*CD + c] = (v[k] - mu) * rs * law[c] + lab[c];
        }
    } else {
        for (int idx = lane; idx < CZD*NH; idx += 64)
            Wp[idx] = lzw[idx >> 4] * Wz[idx];
        if (lane < NH) {
            float P = 0.f, Q = 0.f;
            for (int c = 0; c < CZD; ++c) {
                P += lzw[c] * Wz[c*NH + lane];
                Q += lzb[c] * Wz[c*NH + lane];
            }
            PQ[lane] = P; PQ[NH + lane] = Q;
        }
    }
}

// ---- K1: projections q,k,v,g = an @ {Wq,Wk,Wv,Wg}. 32x64 tile, 128 threads, high occupancy.
__global__ __launch_bounds__(128) void k_proj(
    const float* __restrict__ an, const float* __restrict__ Wq, const float* __restrict__ Wk,
    const float* __restrict__ Wv, const float* __restrict__ Wg, const float* __restrict__ bg,
    float* __restrict__ qm, float* __restrict__ kT, float* __restrict__ vT, float* __restrict__ gm)
{
    __shared__ __align__(16) float Atf[16*36];   // A^T tile [kk][i], pad 36
    __shared__ __align__(16) float Btf[16*68];   // B tile   [kk][n], pad 68
    const int ct = blockIdx.x;              // 24 = 4 matrices x 6 col-tiles
    const int mat = ct / 6;
    const int n0 = (ct % 6) * 64;
    const int i0 = blockIdx.y * 32;
    const float* __restrict__ W = (mat == 0) ? Wq : (mat == 1) ? Wk : (mat == 2) ? Wv : Wg;
    const int t = threadIdx.x;
    const int tr = t >> 4, tc = t & 15;     // tr 0..7, tc 0..15
    float acc[4][4] = {};
    const int kkA = t & 15, iA = t >> 4;    // A stage: rows iA+8s, k kkA
    const int kkB = t >> 6, nB = t & 63;    // B stage: k kkB+2s, col nB
    for (int k0 = 0; k0 < CD; k0 += 16) {
        __syncthreads();
        #pragma unroll
        for (int s = 0; s < 4; ++s)
            Atf[kkA*36 + iA + 8*s] = an[(i0 + iA + 8*s)*CD + k0 + kkA];
        #pragma unroll
        for (int s = 0; s < 8; ++s)
            Btf[(kkB + 2*s)*68 + nB] = W[(k0 + kkB + 2*s)*HCD + n0 + nB];
        __syncthreads();
        #pragma unroll
        for (int kk = 0; kk < 16; ++kk) {
            const float4 a4 = *(const float4*)&Atf[kk*36 + tr*4];
            const float4 b4 = *(const float4*)&Btf[kk*68 + tc*4];
            acc[0][0] += a4.x*b4.x; acc[0][1] += a4.x*b4.y; acc[0][2] += a4.x*b4.z; acc[0][3] += a4.x*b4.w;
            acc[1][0] += a4.y*b4.x; acc[1][1] += a4.y*b4.y; acc[1][2] += a4.y*b4.z; acc[1][3] += a4.y*b4.w;
            acc[2][0] += a4.z*b4.x; acc[2][1] += a4.z*b4.y; acc[2][2] += a4.z*b4.z; acc[2][3] += a4.z*b4.w;
            acc[3][0] += a4.w*b4.x; acc[3][1] += a4.w*b4.y; acc[3][2] += a4.w*b4.z; acc[3][3] += a4.w*b4.w;
        }
    }
    #pragma unroll
    for (int r = 0; r < 4; ++r) {
        const int i = i0 + tr*4 + r;
        #pragma unroll
        for (int c = 0; c < 4; ++c) {
            const int n = n0 + tc*4 + c;
            const float v = acc[r][c];
            if (mat == 0)      qm[i*HCD + n] = v * 0.20412414523193154f;           // * CH^-0.5
            else if (mat == 1) kT[n*NT + i] = v;                                   // k transposed
            else if (mat == 2) vT[n*NT + i] = v;                                   // v transposed
            else               gm[i*HCD + n] = 1.f / (1.f + __expf(-(v + bg[n]))); // sigmoid gate
        }
    }
}

// ---- K2: pair bias. 1 z-row per thread, no LDS, direct float4 reads (L1 catches the
// 16B-of-64B partial-line reuse). bias[h*N*N + r] writes are fully coalesced.
__global__ __launch_bounds__(256) void k_bias(
    const float* __restrict__ z, const float* __restrict__ Wp, const float* __restrict__ PQ,
    float* __restrict__ bias)
{
    const int t = threadIdx.x;
    const size_t r = (size_t)blockIdx.x * 256 + t;
    const float4* __restrict__ zr = (const float4*)(z + r * CZD);
    const float4* __restrict__ Wp4 = (const float4*)Wp;
    float s = 0.f, q = 0.f;
    float acc[16] = {};
    #pragma unroll 8
    for (int c4 = 0; c4 < 32; ++c4) {
        const float4 v = zr[c4];
        const float xs[4] = {v.x, v.y, v.z, v.w};
        #pragma unroll
        for (int e = 0; e < 4; ++e) {
            const float x = xs[e];
            s += x; q += x*x;
            const int c = c4*4 + e;
            const float4 w0 = Wp4[c*4+0], w1 = Wp4[c*4+1], w2 = Wp4[c*4+2], w3 = Wp4[c*4+3];
            acc[0]+=x*w0.x;  acc[1]+=x*w0.y;  acc[2]+=x*w0.z;  acc[3]+=x*w0.w;
            acc[4]+=x*w1.x;  acc[5]+=x*w1.y;  acc[6]+=x*w1.z;  acc[7]+=x*w1.w;
            acc[8]+=x*w2.x;  acc[9]+=x*w2.y;  acc[10]+=x*w2.z; acc[11]+=x*w2.w;
            acc[12]+=x*w3.x; acc[13]+=x*w3.y; acc[14]+=x*w3.z; acc[15]+=x*w3.w;
        }
    }
    const float mu = s * (1.f/CZD);
    const float rs = rsqrtf(q * (1.f/CZD) - mu*mu + 1e-5f);
    #pragma unroll
    for (int h = 0; h < 16; ++h)
        bias[(size_t)h*NT*NT + r] = rs*(acc[h] - mu*PQ[h]) + PQ[16+h];
}

// ---- K3: flash attention with pair bias. Block = (head, 32-row q-tile), 256 threads.
// Thread owns 1 row, 8 key cols per 64-wide tile; per-thread online softmax,
// shfl pair-merge then LDS merge of 4 wave partials.
__global__ __launch_bounds__(256) void k_attn(
    const float* __restrict__ qm, const float* __restrict__ kT, const float* __restrict__ vT,
    const float* __restrict__ bias, const float* __restrict__ mask, float* __restrict__ om)
{
    __shared__ __align__(16) char smem[17408];
    float (*ks)[68] = (float(*)[68])smem;                 // 24*68*4 = 6528
    float (*vs)[28] = (float(*)[28])(smem + 6528);        // 64*28*4 = 7168 -> 13696
    float (*qs)[25] = (float(*)[25])(smem + 13696);       // 32*25*4 = 3200 -> 16896
    float* mb       = (float*)(smem + 16896);             // 64*4 = 256 -> 17152
    // reused after the tile loop (guarded by a barrier):
    float (*po)[32][25] = (float(*)[32][25])smem;         // 4*32*25*4 = 12800
    float* pmf      = (float*)(smem + 12800);             // 128*4 = 512
    float* plf      = (float*)(smem + 13312);             // 512

    const int h  = blockIdx.x;
    const int i0 = blockIdx.y * 32;
    const int t = threadIdx.x;
    const int lane = t & 63, wave = t >> 6;
    const int i2 = lane & 31;
    const int jg8 = ((wave << 1) + (lane >> 5)) * 8;   // this thread's 8 key cols in tile

    for (int idx = t; idx < 32*CHD; idx += 256) {
        const int ii = idx / CHD, c = idx % CHD;
        qs[ii][c] = qm[(i0+ii)*HCD + h*CHD + c];
    }
    __syncthreads();
    float qr[24];
    #pragma unroll
    for (int c = 0; c < 24; ++c) qr[c] = qs[i2][c];
    float m_ = -1e30f, l_ = 0.f;
    float ov[24] = {};

    for (int jt = 0; jt < NT; jt += 64) {
        __syncthreads();
        for (int idx = t; idx < 24*64; idx += 256) {
            const int c = idx >> 6, j = idx & 63;
            ks[c][j] = kT[(h*CHD + c)*NT + jt + j];
            vs[j][c] = vT[(h*CHD + c)*NT + jt + j];
        }
        if (t < 64) mb[t] = 1e9f * (mask[jt + t] - 1.f);
        __syncthreads();

        const float* bp = bias + ((size_t)h*NT + (size_t)(i0 + i2))*NT + jt + jg8;
        const float4 b0 = *(const float4*)bp;
        const float4 b1 = *(const float4*)(bp + 4);
        float sc[8] = {b0.x, b0.y, b0.z, b0.w, b1.x, b1.y, b1.z, b1.w};
        #pragma unroll
        for (int jj = 0; jj < 8; ++jj) sc[jj] += mb[jg8+jj];
        #pragma unroll
        for (int c = 0; c < 24; ++c) {
            const float4 k4a = *(const float4*)&ks[c][jg8];
            const float4 k4b = *(const float4*)&ks[c][jg8+4];
            const float q0 = qr[c];
            sc[0] += q0*k4a.x; sc[1] += q0*k4a.y; sc[2] += q0*k4a.z; sc[3] += q0*k4a.w;
            sc[4] += q0*k4b.x; sc[5] += q0*k4b.y; sc[6] += q0*k4b.z; sc[7] += q0*k4b.w;
        }
        float mt = sc[0];
        #pragma unroll
        for (int jj = 1; jj < 8; ++jj) mt = fmaxf(mt, sc[jj]);
        const float mn = fmaxf(m_, mt);
        const float al = __expf(m_ - mn);
        m_ = mn;
        float p[8], ps = 0.f;
        #pragma unroll
        for (int jj = 0; jj < 8; ++jj) { p[jj] = __expf(sc[jj] - mn); ps += p[jj]; }
        l_ = l_*al + ps;
        #pragma unroll
        for (int c = 0; c < 24; ++c) ov[c] *= al;
        #pragma unroll
        for (int jj = 0; jj < 8; ++jj) {
            #pragma unroll
            for (int c4 = 0; c4 < 6; ++c4) {
                const float4 v4 = *(const float4*)&vs[jg8+jj][c4*4];
                ov[c4*4+0] += p[jj]*v4.x; ov[c4*4+1] += p[jj]*v4.y;
                ov[c4*4+2] += p[jj]*v4.z; ov[c4*4+3] += p[jj]*v4.w;
            }
        }
    }
    // pair-merge the two half-wave partials (same row, neighboring j-groups)
    {
        const float mo = __shfl_xor(m_, 32);
        const float lo = __shfl_xor(l_, 32);
        const float mn = fmaxf(m_, mo);
        const float wa = __expf(m_ - mn), wb = __expf(mo - mn);
        l_ = l_*wa + lo*wb;
        m_ = mn;
        #pragma unroll
        for (int c = 0; c < 24; ++c)
            ov[c] = ov[c]*wa + __shfl_xor(ov[c], 32)*wb;
    }
    __syncthreads();   // tile-loop LDS reads done; smem reused for partials
    if (lane < 32) {
        pmf[wave*32 + i2] = m_; plf[wave*32 + i2] = l_;
        #pragma unroll
        for (int c = 0; c < 24; ++c) po[wave][i2][c] = ov[c];
    }
    __syncthreads();
    {
        const int i = t & 31, cq = t >> 5;   // cq 0..7 -> 3 channels each
        float ms = -1e30f;
        #pragma unroll
        for (int g = 0; g < 4; ++g) ms = fmaxf(ms, pmf[g*32 + i]);
        float ls = 0.f, o0 = 0.f, o1 = 0.f, o2 = 0.f;
        #pragma unroll
        for (int g = 0; g < 4; ++g) {
            const float w = __expf(pmf[g*32 + i] - ms);
            ls += w * plf[g*32 + i];
            o0 += w * po[g][i][cq*3+0];
            o1 += w * po[g][i][cq*3+1];
            o2 += w * po[g][i][cq*3+2];
        }
        const float inv = 1.f / ls;
        float* dst = om + (size_t)(i0 + i)*HCD + h*CHD + cq*3;
        dst[0] = o0*inv; dst[1] = o1*inv; dst[2] = o2*inv;
    }
}

// ---- K4: out = (g*o) @ Wo + bo. 32x64 tile, 128 threads.
__global__ __launch_bounds__(128) void k_epi(
    const float* __restrict__ gm, const float* __restrict__ om, const float* __restrict__ Wo,
    const float* __restrict__ bo, float* __restrict__ out)
{
    __shared__ __align__(16) float Atf[16*36];
    __shared__ __align__(16) float Btf[16*68];
    const int n0 = blockIdx.x * 64;
    const int i0 = blockIdx.y * 32;
    const int t = threadIdx.x;
    const int tr = t >> 4, tc = t & 15;
    float acc[4][4] = {};
    const int kkA = t & 15, iA = t >> 4;
    const int kkB = t >> 6, nB = t & 63;
    for (int k0 = 0; k0 < HCD; k0 += 16) {
        __syncthreads();
        #pragma unroll
        for (int s = 0; s < 4; ++s) {
            const int row = i0 + iA + 8*s;
            Atf[kkA*36 + iA + 8*s] = gm[row*HCD + k0 + kkA] * om[row*HCD + k0 + kkA];
        }
        #pragma unroll
        for (int s = 0; s < 8; ++s)
            Btf[(kkB + 2*s)*68 + nB] = Wo[(k0 + kkB + 2*s)*CD + n0 + nB];
        __syncthreads();
        #pragma unroll
        for (int kk = 0; kk < 16; ++kk) {
            const float4 a4 = *(const float4*)&Atf[kk*36 + tr*4];
            const float4 b4 = *(const float4*)&Btf[kk*68 + tc*4];
            acc[0][0] += a4.x*b4.x; acc[0][1] += a4.x*b4.y; acc[0][2] += a4.x*b4.z; acc[0][3] += a4.x*b4.w;
            acc[1][0] += a4.y*b4.x; acc[1][1] += a4.y*b4.y; acc[1][2] += a4.y*b4.z; acc[1][3] += a4.y*b4.w;
            acc[2][0] += a4.z*b4.x; acc[2][1] += a4.z*b4.y; acc[2][2] += a4.z*b4.z; acc[2][3] += a4.z*b4.w;
            acc[3][0] += a4.w*b4.x; acc[3][1] += a4.w*b4.y; acc[3][2] += a4.w*b4.z; acc[3][3] += a4.w*b4.w;
        }
    }
    #pragma unroll
    for (int r = 0; r < 4; ++r) {
        const int i = i0 + tr*4 + r;
        #pragma unroll
        for (int c = 0; c < 4; ++c) {
            const int n = n0 + tc*4 + c;
            out[i*CD + n] = acc[r][c] + bo[n];
        }
    }
}

extern "C" void kernel_launch(void* const* d_in, const int* in_sizes, int n_in,
                              void* d_out, int out_size, void* d_ws, size_t ws_size,
                              hipStream_t stream) {
    const float* a    = (const float*)d_in[0];
    const float* z    = (const float*)d_in[1];
    const float* mask = (const float*)d_in[2];
    const float* law  = (const float*)d_in[3];
    const float* lab  = (const float*)d_in[4];
    const float* lzw  = (const float*)d_in[5];
    const float* lzb  = (const float*)d_in[6];
    const float* Wz   = (const float*)d_in[7];
    const float* Wq   = (const float*)d_in[8];
    const float* Wk   = (const float*)d_in[9];
    const float* Wv   = (const float*)d_in[10];
    const float* Wg   = (const float*)d_in[11];
    const float* bg   = (const float*)d_in[12];
    const float* Wo   = (const float*)d_in[13];
    const float* bo   = (const float*)d_in[14];
    float* out = (float*)d_out;

    float* ws = (float*)d_ws;
    float* an   = ws;                  // 768*384
    float* qm   = an + 294912;
    float* kT   = qm + 294912;
    float* vT   = kT + 294912;
    float* gm   = vT + 294912;
    float* om   = gm + 294912;
    float* Wp   = om + 294912;         // 128*16
    float* PQ   = Wp + 2048;           // 32
    float* bias = PQ + 32;             // 16*768*768

    k_prep<<<769, 64, 0, stream>>>(a, law, lab, lzw, lzb, Wz, an, Wp, PQ);
    k_proj<<<dim3(24, 24), 128, 0, stream>>>(an, Wq, Wk, Wv, Wg, bg, qm, kT, vT, gm);
    k_bias<<<2304, 256, 0, stream>>>(z, Wp, PQ, bias);
    k_attn<<<dim3(16, 24), 256, 0, stream>>>(qm, kT, vT, bias, mask, om);
    k_epi<<<dim3(6, 24), 128, 0, stream>>>(gm, om, Wo, bo, out);
}